// Round 6
// baseline (803.787 us; speedup 1.0000x reference)
//
#include <hip/hip_runtime.h>
#include <hip/hip_fp16.h>

#define N_USERS 50000
#define N_ITEMS 75000
#define N_NODES (N_USERS + N_ITEMS)   // 125000
#define NNZ     1250000
#define EMB     64
#define N_LAYERS 3
#define BATCH   4096
#define CONCAT  (EMB * (N_LAYERS + 1)) // 256
#define NBLK_SCAN ((N_NODES + 1023) / 1024)  // 123

// 'user' may be int64 (jax x64) or int32. Detect from data.
__device__ __forceinline__ bool user_is_i64(const void* uptr) {
    const int* u = (const int*)uptr;
    return (u[1] | u[3] | u[5] | u[7]) == 0;
}
__device__ __forceinline__ int load_user(const void* uptr, int b, bool is64) {
    return is64 ? (int)((const long long*)uptr)[b] : ((const int*)uptr)[b];
}
__device__ __forceinline__ int sample_node(const void* user, const int* pos,
                                           const int* neg, int which, int b,
                                           bool is64) {
    if (which == 0) return load_user(user, b, is64);
    return N_USERS + (which == 1 ? pos[b] : neg[b]);
}

// ---------------------------------------------------------------------------
// init: feat32 <- emb, feat16 <- fp16(emb)
// ---------------------------------------------------------------------------
__global__ void init_kernel(const float* __restrict__ emb,
                            float* __restrict__ feat32,
                            __half* __restrict__ feat16) {
    int i = blockIdx.x * blockDim.x + threadIdx.x;
    if (i >= N_NODES * EMB) return;
    float v = emb[i];
    feat32[i] = v;
    feat16[i] = __float2half(v);
}

__global__ void gather0_kernel(const void* __restrict__ user,
                               const int* __restrict__ pos,
                               const int* __restrict__ neg,
                               const float* __restrict__ emb,
                               float* __restrict__ out) {
    int i = blockIdx.x * blockDim.x + threadIdx.x;  // 3*BATCH*64
    if (i >= 3 * BATCH * EMB) return;
    bool is64 = user_is_i64(user);
    int which = i / (BATCH * EMB);
    int rem   = i % (BATCH * EMB);
    int b = rem >> 6, d = rem & 63;
    int node = sample_node(user, pos, neg, which, b, is64);
    out[(which * BATCH + b) * CONCAT + d] = emb[node * EMB + d];
}

// ---------------------------------------------------------------------------
// CSR build: histogram -> exclusive scan -> bin edges (row-sorted int2 payload)
// ---------------------------------------------------------------------------
__global__ void count_kernel(const int* __restrict__ row, int* __restrict__ cnt) {
    int e = blockIdx.x * 256 + threadIdx.x;
    if (e < NNZ) atomicAdd(&cnt[row[e]], 1);
}

__global__ __launch_bounds__(256) void scan_blocks_kernel(
    const int* __restrict__ cnt, int* __restrict__ off, int* __restrict__ bsum) {
    __shared__ int s[256];
    int t = threadIdx.x, b = blockIdx.x;
    int base = b * 1024 + t * 4;
    int v0 = (base + 0 < N_NODES) ? cnt[base + 0] : 0;
    int v1 = (base + 1 < N_NODES) ? cnt[base + 1] : 0;
    int v2 = (base + 2 < N_NODES) ? cnt[base + 2] : 0;
    int v3 = (base + 3 < N_NODES) ? cnt[base + 3] : 0;
    int tsum = v0 + v1 + v2 + v3;
    s[t] = tsum;
    __syncthreads();
    for (int d = 1; d < 256; d <<= 1) {   // Hillis-Steele inclusive scan
        int x = (t >= d) ? s[t - d] : 0;
        __syncthreads();
        s[t] += x;
        __syncthreads();
    }
    int excl = s[t] - tsum;
    if (base + 0 < N_NODES) off[base + 0] = excl;
    if (base + 1 < N_NODES) off[base + 1] = excl + v0;
    if (base + 2 < N_NODES) off[base + 2] = excl + v0 + v1;
    if (base + 3 < N_NODES) off[base + 3] = excl + v0 + v1 + v2;
    if (t == 255) bsum[b] = s[255];
}

__global__ void scan_tops_kernel(int* __restrict__ bsum) {
    if (blockIdx.x == 0 && threadIdx.x == 0) {
        int run = 0;
        for (int b = 0; b < NBLK_SCAN; ++b) { int x = bsum[b]; bsum[b] = run; run += x; }
    }
}

__global__ void scan_add_kernel(int* __restrict__ off, const int* __restrict__ bsum,
                                int* __restrict__ cursor) {
    int i = blockIdx.x * 256 + threadIdx.x;
    if (i < N_NODES) {
        int v = off[i] + bsum[i >> 10];
        off[i] = v;
        cursor[i] = v;
    }
    if (i == 0) off[N_NODES] = NNZ;
}

__global__ void bin_kernel(const int* __restrict__ row, const int* __restrict__ col,
                           const float* __restrict__ vals,
                           int* __restrict__ cursor, int2* __restrict__ se) {
    int e = blockIdx.x * 256 + threadIdx.x;
    if (e >= NNZ) return;
    int r = row[e];
    int p = atomicAdd(&cursor[r], 1);
    se[p] = make_int2(col[e], __float_as_int(vals[e]));
}

// ---------------------------------------------------------------------------
// fused per-layer: one wave per node (grid-stride).
//   agg = sum_e val_e * feat16_in[col_e]          (gather, fp16 rows = 128B)
//   p1 = lrelu(agg @ W1^T + b1); p2 = lrelu((agg*feat32) @ W2^T + b2)
//   feat32[n] <- p1+p2 (in place; only this wave touches row n)
//   feat16_out[n] <- fp16(p1+p2)
// Edge records loaded ONCE per wave (lane t holds edge t), __shfl broadcast.
// Lane d holds W1/W2 row d in registers; agg/g rows broadcast via LDS b128.
// ---------------------------------------------------------------------------
__global__ __launch_bounds__(256) void fused_kernel(
    const int* __restrict__ off, const int2* __restrict__ se,
    const __half* __restrict__ fin, float* __restrict__ feat32,
    __half* __restrict__ fout,
    const float* __restrict__ W1, const float* __restrict__ b1,
    const float* __restrict__ W2, const float* __restrict__ b2,
    int layer) {

    __shared__ float w1s[EMB * 65];   // padded: w1s[d*65+k] = W1[l][d][k]
    __shared__ float w2s[EMB * 65];
    __shared__ float sa[4][EMB];
    __shared__ float sg[4][EMB];

    const int tid = threadIdx.x, wave = tid >> 6, lane = tid & 63;
    const float* W1l = W1 + layer * EMB * EMB;
    const float* W2l = W2 + layer * EMB * EMB;
    for (int j = tid; j < EMB * EMB; j += 256) {
        int d = j >> 6, k = j & 63;
        w1s[d * 65 + k] = W1l[j];
        w2s[d * 65 + k] = W2l[j];
    }
    __syncthreads();

    float w1r[EMB], w2r[EMB];
    #pragma unroll
    for (int k = 0; k < EMB; ++k) {   // bank (lane+k)%32: 2-way = free
        w1r[k] = w1s[lane * 65 + k];
        w2r[k] = w2s[lane * 65 + k];
    }
    const float bias1 = b1[layer * EMB + lane];
    const float bias2 = b2[layer * EMB + lane];

    const int nwaves = gridDim.x * 4;
    for (int n = blockIdx.x * 4 + wave; n < N_NODES; n += nwaves) {
        int j = off[n], end = off[n + 1];
        float acc = 0.f;
        while (j < end) {
            int c = end - j; if (c > 64) c = 64;
            int2 e = se[j + (lane < c ? lane : 0)];   // one 8B load per lane
            for (int t = 0; t < c; t += 4) {
                #pragma unroll
                for (int i = 0; i < 4; ++i) {
                    int tt = t + i;
                    int colv = __shfl(e.x, tt & 63, 64);
                    int valb = __shfl(e.y, tt & 63, 64);
                    float v  = (tt < c) ? __int_as_float(valb) : 0.f;
                    int cidx = (tt < c) ? colv : 0;
                    acc += v * __half2float(fin[cidx * EMB + lane]);
                }
            }
            j += c;
        }

        float f = feat32[n * EMB + lane];
        float g = acc * f;
        sa[wave][lane] = acc;        // same-wave LDS write->read: ordered
        sg[wave][lane] = g;

        float acc1 = bias1, acc2 = bias2;
        #pragma unroll
        for (int kq = 0; kq < 16; ++kq) {
            float4 av = *(const float4*)&sa[wave][kq * 4];  // broadcast b128
            float4 gv = *(const float4*)&sg[wave][kq * 4];
            acc1 += av.x * w1r[4*kq+0] + av.y * w1r[4*kq+1]
                  + av.z * w1r[4*kq+2] + av.w * w1r[4*kq+3];
            acc2 += gv.x * w2r[4*kq+0] + gv.y * w2r[4*kq+1]
                  + gv.z * w2r[4*kq+2] + gv.w * w2r[4*kq+3];
        }
        float p1 = acc1 > 0.f ? acc1 : 0.2f * acc1;
        float p2 = acc2 > 0.f ? acc2 : 0.2f * acc2;
        float nf = p1 + p2;
        feat32[n * EMB + lane] = nf;
        fout[n * EMB + lane] = __float2half(nf);
    }
}

// ---------------------------------------------------------------------------
__global__ __launch_bounds__(256) void gatherL_kernel(
    const void* __restrict__ user, const int* __restrict__ pos,
    const int* __restrict__ neg, const float* __restrict__ feat32,
    float* __restrict__ out, int layer) {

    int w = blockIdx.x * 4 + (threadIdx.x >> 6);
    int lane = threadIdx.x & 63;
    if (w >= 3 * BATCH) return;
    bool is64 = user_is_i64(user);
    int which = w / BATCH, b = w % BATCH;
    int node = sample_node(user, pos, neg, which, b, is64);

    float f = feat32[node * EMB + lane];
    float sq = f * f;
    #pragma unroll
    for (int off = 32; off; off >>= 1) sq += __shfl_xor(sq, off, 64);
    float norm = fmaxf(sqrtf(sq), 1e-12f);

    out[w * CONCAT + (layer + 1) * EMB + lane] = f / norm;
}

extern "C" void kernel_launch(void* const* d_in, const int* in_sizes, int n_in,
                              void* d_out, int out_size, void* d_ws, size_t ws_size,
                              hipStream_t stream) {
    const void* user = d_in[0];
    const int* pos  = (const int*)d_in[1];
    const int* neg  = (const int*)d_in[2];
    const int* row  = (const int*)d_in[3];
    const int* col  = (const int*)d_in[4];
    const float* vals = (const float*)d_in[5];
    const float* emb  = (const float*)d_in[6];
    const float* W1   = (const float*)d_in[7];
    const float* b1   = (const float*)d_in[8];
    const float* W2   = (const float*)d_in[9];
    const float* b2   = (const float*)d_in[10];

    // workspace: feat32 32MB | f16a 16MB | f16b 16MB | ints ~1.5MB | se 10MB
    float*  feat32 = (float*)d_ws;
    __half* f16a   = (__half*)(feat32 + (size_t)N_NODES * EMB);
    __half* f16b   = f16a + (size_t)N_NODES * EMB;
    int*    off    = (int*)(f16b + (size_t)N_NODES * EMB);
    int*    cursor = off + 125008;          // off needs N_NODES+1; padded
    int*    cnt    = cursor + N_NODES;
    int*    bsum   = cnt + N_NODES;         // NBLK_SCAN=123, padded to 128
    int2*   se     = (int2*)(bsum + 128);   // byte offset divisible by 8

    float* out = (float*)d_out;

    // --- CSR build (once per launch) ---
    hipMemsetAsync(cnt, 0, (size_t)N_NODES * sizeof(int), stream);
    count_kernel<<<(NNZ + 255) / 256, 256, 0, stream>>>(row, cnt);
    scan_blocks_kernel<<<NBLK_SCAN, 256, 0, stream>>>(cnt, off, bsum);
    scan_tops_kernel<<<1, 64, 0, stream>>>(bsum);
    scan_add_kernel<<<(N_NODES + 255) / 256, 256, 0, stream>>>(off, bsum, cursor);
    bin_kernel<<<(NNZ + 255) / 256, 256, 0, stream>>>(row, col, vals, cursor, se);

    init_kernel<<<(N_NODES * EMB + 255) / 256, 256, 0, stream>>>(emb, feat32, f16a);
    gather0_kernel<<<(3 * BATCH * EMB + 255) / 256, 256, 0, stream>>>(
        user, pos, neg, emb, out);

    const __half* fin = f16a;
    __half* fout = f16b;
    for (int l = 0; l < N_LAYERS; ++l) {
        fused_kernel<<<2048, 256, 0, stream>>>(off, se, fin, feat32, fout,
                                               W1, b1, W2, b2, l);
        gatherL_kernel<<<(3 * BATCH + 3) / 4, 256, 0, stream>>>(
            user, pos, neg, feat32, out, l);
        const __half* tmp = fout; fout = (__half*)fin; fin = tmp;
    }
}

// Round 7
// 586.746 us; speedup vs baseline: 1.3699x; 1.3699x over previous
//
#include <hip/hip_runtime.h>
#include <hip/hip_fp16.h>

#define N_USERS 50000
#define N_ITEMS 75000
#define N_NODES 125000
#define N_PAD   125008               // padded to multiple of 16 for MFMA tiles
#define NNZ     1250000
#define EMB     64
#define N_LAYERS 3
#define BATCH   4096
#define CONCAT  256
#define NBLK_SCAN ((N_NODES + 1023) / 1024)   // 123
#define NTILES  ((N_NODES + 15) / 16)         // 7813

typedef _Float16 half8  __attribute__((ext_vector_type(8)));
typedef float    floatx4 __attribute__((ext_vector_type(4)));

// 'user' may be int64 (jax x64) or int32. Detect from data.
__device__ __forceinline__ bool user_is_i64(const void* uptr) {
    const int* u = (const int*)uptr;
    return (u[1] | u[3] | u[5] | u[7]) == 0;
}
__device__ __forceinline__ int load_user(const void* uptr, int b, bool is64) {
    return is64 ? (int)((const long long*)uptr)[b] : ((const int*)uptr)[b];
}
__device__ __forceinline__ int sample_node(const void* user, const int* pos,
                                           const int* neg, int which, int b,
                                           bool is64) {
    if (which == 0) return load_user(user, b, is64);
    return N_USERS + (which == 1 ? pos[b] : neg[b]);
}

// ---------------------------------------------------------------------------
// init (+ fused gather0): feat32 <- emb, f16 <- fp16(emb); out[:, 0:64] <- emb rows
// N_NODES*EMB = 8,000,000 = 31250 blocks exactly; gather0 rides on blocks after.
// ---------------------------------------------------------------------------
__global__ void init_kernel(const float* __restrict__ emb,
                            float* __restrict__ feat32,
                            _Float16* __restrict__ f16,
                            const void* __restrict__ user,
                            const int* __restrict__ pos,
                            const int* __restrict__ neg,
                            float* __restrict__ out) {
    int i = blockIdx.x * 256 + threadIdx.x;
    if (i < N_NODES * EMB) {
        float v = emb[i];
        feat32[i] = v;
        f16[i] = (_Float16)v;
    } else {
        int j = i - N_NODES * EMB;
        if (j < 3 * BATCH * EMB) {
            bool is64 = user_is_i64(user);
            int which = j / (BATCH * EMB);
            int rem   = j % (BATCH * EMB);
            int b = rem >> 6, d = rem & 63;
            int node = sample_node(user, pos, neg, which, b, is64);
            out[(which * BATCH + b) * CONCAT + d] = emb[node * EMB + d];
        }
    }
}

// ---------------------------------------------------------------------------
// CSR build: histogram -> scan -> bin (row-sorted int2 payload)
// ---------------------------------------------------------------------------
__global__ void count_kernel(const int* __restrict__ row, int* __restrict__ cnt) {
    int e = blockIdx.x * 256 + threadIdx.x;
    if (e < NNZ) atomicAdd(&cnt[row[e]], 1);
}

__global__ __launch_bounds__(256) void scan_blocks_kernel(
    const int* __restrict__ cnt, int* __restrict__ off, int* __restrict__ bsum) {
    __shared__ int s[256];
    int t = threadIdx.x, b = blockIdx.x;
    int base = b * 1024 + t * 4;
    int v0 = (base + 0 < N_NODES) ? cnt[base + 0] : 0;
    int v1 = (base + 1 < N_NODES) ? cnt[base + 1] : 0;
    int v2 = (base + 2 < N_NODES) ? cnt[base + 2] : 0;
    int v3 = (base + 3 < N_NODES) ? cnt[base + 3] : 0;
    int tsum = v0 + v1 + v2 + v3;
    s[t] = tsum;
    __syncthreads();
    for (int d = 1; d < 256; d <<= 1) {
        int x = (t >= d) ? s[t - d] : 0;
        __syncthreads();
        s[t] += x;
        __syncthreads();
    }
    int excl = s[t] - tsum;
    if (base + 0 < N_NODES) off[base + 0] = excl;
    if (base + 1 < N_NODES) off[base + 1] = excl + v0;
    if (base + 2 < N_NODES) off[base + 2] = excl + v0 + v1;
    if (base + 3 < N_NODES) off[base + 3] = excl + v0 + v1 + v2;
    if (t == 255) bsum[b] = s[255];
}

// merged: per-block redundant prefix of bsum (123 entries) + add
__global__ __launch_bounds__(256) void scan_add_kernel(
    int* __restrict__ off, const int* __restrict__ bsum, int* __restrict__ cursor) {
    __shared__ int sb[NBLK_SCAN];
    int t = threadIdx.x;
    if (t < NBLK_SCAN) sb[t] = bsum[t];
    __syncthreads();
    if (t == 0) {
        int run = 0;
        for (int b = 0; b < NBLK_SCAN; ++b) { int x = sb[b]; sb[b] = run; run += x; }
    }
    __syncthreads();
    int i = blockIdx.x * 256 + t;
    if (i < N_NODES) {
        int v = off[i] + sb[i >> 10];
        off[i] = v;
        cursor[i] = v;
    }
    if (i == 0) off[N_NODES] = NNZ;
}

__global__ void bin_kernel(const int* __restrict__ row, const int* __restrict__ col,
                           const float* __restrict__ vals,
                           int* __restrict__ cursor, int2* __restrict__ se) {
    int e = blockIdx.x * 256 + threadIdx.x;
    if (e >= NNZ) return;
    int r = row[e];
    int p = atomicAdd(&cursor[r], 1);
    se[p] = make_int2(col[e], __float_as_int(vals[e]));
}

// ---------------------------------------------------------------------------
// SpMM gather (round-5 proven shape, fp16 rows): one wave per node.
//   agg16[n] = fp16( sum_e val_e * fin[col_e] )
// ---------------------------------------------------------------------------
__global__ __launch_bounds__(256) void spmm_kernel(
    const int* __restrict__ off, const int2* __restrict__ se,
    const _Float16* __restrict__ fin, _Float16* __restrict__ agg16) {
    int w = blockIdx.x * 4 + (threadIdx.x >> 6);
    int lane = threadIdx.x & 63;
    if (w >= N_NODES) return;
    int j = off[w], end = off[w + 1];
    float acc = 0.f;
    while (j < end) {
        int cnt = end - j;
        int2 ev[8];
        #pragma unroll
        for (int t = 0; t < 8; ++t)
            ev[t] = (t < cnt) ? se[j + t] : make_int2(0, 0);  // val bits 0 => 0.0f
        #pragma unroll
        for (int t = 0; t < 8; ++t)
            acc += __int_as_float(ev[t].y) * (float)fin[ev[t].x * EMB + lane];
        j += 8;
    }
    agg16[w * EMB + lane] = (_Float16)acc;
}

// ---------------------------------------------------------------------------
// dense via MFMA f16: one wave = 16 nodes x 64 dims (4 n-tiles of 16).
//   p1 = lrelu(agg @ W1^T + b1); p2 = lrelu((agg*fin) @ W2^T + b2)
//   feat32 <- p1+p2 ; fout16 <- fp16(p1+p2)
// Layouts (gfx950, verified): A[m=lane&15][k=quad*8+j]; B[k=quad*8+j][n=lane&15];
// D: col=lane&15, row=quad*4+reg. g-frag = a-frag * f-frag elementwise (same [m][k]).
// ---------------------------------------------------------------------------
__global__ __launch_bounds__(256) void dense_kernel(
    const _Float16* __restrict__ agg16, const _Float16* __restrict__ fin,
    float* __restrict__ feat32, _Float16* __restrict__ fout,
    const float* __restrict__ W1, const float* __restrict__ b1,
    const float* __restrict__ W2, const float* __restrict__ b2, int layer) {

    const int tid = threadIdx.x, wave = tid >> 6, lane = tid & 63;
    const int quad = lane >> 4, lm = lane & 15;

    // Preload B-fragments (fp16 in registers): bwX[t][kh], t = n-tile, kh = K half
    half8 bw1[4][2], bw2[4][2];
    float bias1[4], bias2[4];
    const float* W1l = W1 + layer * EMB * EMB;
    const float* W2l = W2 + layer * EMB * EMB;
    #pragma unroll
    for (int t = 0; t < 4; ++t) {
        int n = t * 16 + lm;
        bias1[t] = b1[layer * EMB + n];
        bias2[t] = b2[layer * EMB + n];
        #pragma unroll
        for (int kh = 0; kh < 2; ++kh) {
            const float* p1 = W1l + n * EMB + kh * 32 + quad * 8;
            const float* p2 = W2l + n * EMB + kh * 32 + quad * 8;
            floatx4 wa = *(const floatx4*)p1, wb = *(const floatx4*)(p1 + 4);
            floatx4 xa = *(const floatx4*)p2, xb = *(const floatx4*)(p2 + 4);
            half8 h1, h2;
            #pragma unroll
            for (int i = 0; i < 4; ++i) {
                h1[i] = (_Float16)wa[i]; h1[4 + i] = (_Float16)wb[i];
                h2[i] = (_Float16)xa[i]; h2[4 + i] = (_Float16)xb[i];
            }
            bw1[t][kh] = h1;
            bw2[t][kh] = h2;
        }
    }

    for (int tile = blockIdx.x * 4 + wave; tile < NTILES; tile += gridDim.x * 4) {
        int nb = tile * 16;
        const half8* ap = (const half8*)(agg16 + (size_t)(nb + lm) * EMB + quad * 8);
        const half8* fp = (const half8*)(fin   + (size_t)(nb + lm) * EMB + quad * 8);
        half8 a0 = ap[0], a1 = ap[4];   // k in [0,32) and [32,64)
        half8 f0 = fp[0], f1 = fp[4];
        half8 g0 = a0 * f0, g1 = a1 * f1;   // v_pk_mul_f16, frag-space elementwise

        #pragma unroll
        for (int t = 0; t < 4; ++t) {
            floatx4 d1 = {0.f, 0.f, 0.f, 0.f}, d2 = {0.f, 0.f, 0.f, 0.f};
            d1 = __builtin_amdgcn_mfma_f32_16x16x32_f16(a0, bw1[t][0], d1, 0, 0, 0);
            d1 = __builtin_amdgcn_mfma_f32_16x16x32_f16(a1, bw1[t][1], d1, 0, 0, 0);
            d2 = __builtin_amdgcn_mfma_f32_16x16x32_f16(g0, bw2[t][0], d2, 0, 0, 0);
            d2 = __builtin_amdgcn_mfma_f32_16x16x32_f16(g1, bw2[t][1], d2, 0, 0, 0);
            int dim = t * 16 + lm;
            #pragma unroll
            for (int r = 0; r < 4; ++r) {
                int node = nb + quad * 4 + r;
                float p1v = d1[r] + bias1[t];
                p1v = p1v > 0.f ? p1v : 0.2f * p1v;
                float p2v = d2[r] + bias2[t];
                p2v = p2v > 0.f ? p2v : 0.2f * p2v;
                float nf = p1v + p2v;
                if (node < N_NODES) {
                    feat32[(size_t)node * EMB + dim] = nf;
                    fout[(size_t)node * EMB + dim] = (_Float16)nf;
                }
            }
        }
    }
}

// ---------------------------------------------------------------------------
__global__ __launch_bounds__(256) void gatherL_kernel(
    const void* __restrict__ user, const int* __restrict__ pos,
    const int* __restrict__ neg, const float* __restrict__ feat32,
    float* __restrict__ out, int layer) {

    int w = blockIdx.x * 4 + (threadIdx.x >> 6);
    int lane = threadIdx.x & 63;
    if (w >= 3 * BATCH) return;
    bool is64 = user_is_i64(user);
    int which = w / BATCH, b = w % BATCH;
    int node = sample_node(user, pos, neg, which, b, is64);

    float f = feat32[node * EMB + lane];
    float sq = f * f;
    #pragma unroll
    for (int off = 32; off; off >>= 1) sq += __shfl_xor(sq, off, 64);
    float norm = fmaxf(sqrtf(sq), 1e-12f);

    out[w * CONCAT + (layer + 1) * EMB + lane] = f / norm;
}

extern "C" void kernel_launch(void* const* d_in, const int* in_sizes, int n_in,
                              void* d_out, int out_size, void* d_ws, size_t ws_size,
                              hipStream_t stream) {
    const void* user = d_in[0];
    const int* pos  = (const int*)d_in[1];
    const int* neg  = (const int*)d_in[2];
    const int* row  = (const int*)d_in[3];
    const int* col  = (const int*)d_in[4];
    const float* vals = (const float*)d_in[5];
    const float* emb  = (const float*)d_in[6];
    const float* W1   = (const float*)d_in[7];
    const float* b1   = (const float*)d_in[8];
    const float* W2   = (const float*)d_in[9];
    const float* b2   = (const float*)d_in[10];

    // ws: feat32 32MB | f16a 16MB | f16b 16MB | agg16 16MB | ints ~1.9MB | se 10MB
    float*    feat32 = (float*)d_ws;
    _Float16* f16a   = (_Float16*)(feat32 + (size_t)N_PAD * EMB);
    _Float16* f16b   = f16a + (size_t)N_PAD * EMB;
    _Float16* agg16  = f16b + (size_t)N_PAD * EMB;
    int*      off    = (int*)(agg16 + (size_t)N_PAD * EMB);
    int*      cursor = off + (N_NODES + 8);
    int*      cnt    = cursor + N_NODES;
    int*      bsum   = cnt + N_NODES;       // 123, padded to 128
    int2*     se     = (int2*)(bsum + 128); // byte offset divisible by 8

    float* out = (float*)d_out;

    // --- CSR build ---
    hipMemsetAsync(cnt, 0, (size_t)N_NODES * sizeof(int), stream);
    count_kernel<<<(NNZ + 255) / 256, 256, 0, stream>>>(row, cnt);
    scan_blocks_kernel<<<NBLK_SCAN, 256, 0, stream>>>(cnt, off, bsum);
    scan_add_kernel<<<(N_NODES + 255) / 256, 256, 0, stream>>>(off, bsum, cursor);
    bin_kernel<<<(NNZ + 255) / 256, 256, 0, stream>>>(row, col, vals, cursor, se);

    // --- init + gather0 fused ---
    init_kernel<<<(N_NODES * EMB + 3 * BATCH * EMB + 255) / 256, 256, 0, stream>>>(
        emb, feat32, f16a, user, pos, neg, out);

    const _Float16* fin = f16a;
    _Float16* fout = f16b;
    for (int l = 0; l < N_LAYERS; ++l) {
        spmm_kernel<<<(N_NODES + 3) / 4, 256, 0, stream>>>(off, se, fin, agg16);
        dense_kernel<<<1024, 256, 0, stream>>>(agg16, fin, feat32, fout,
                                               W1, b1, W2, b2, l);
        gatherL_kernel<<<(3 * BATCH + 3) / 4, 256, 0, stream>>>(
            user, pos, neg, feat32, out, l);
        const _Float16* tmp = fout; fout = (_Float16*)fin; fin = tmp;
    }
}

// Round 8
// 452.695 us; speedup vs baseline: 1.7756x; 1.2961x over previous
//
#include <hip/hip_runtime.h>
#include <hip/hip_fp16.h>

#define N_USERS 50000
#define N_ITEMS 75000
#define N_NODES 125000
#define N_PAD   125008               // padded to multiple of 16 for MFMA tiles
#define NNZ     1250000
#define EMB     64
#define N_LAYERS 3
#define BATCH   4096
#define CONCAT  256
#define NBLK_SCAN ((N_NODES + 1023) / 1024)   // 123
#define NTILES  ((N_NODES + 15) / 16)         // 7813

typedef _Float16 half8  __attribute__((ext_vector_type(8)));
typedef float    floatx4 __attribute__((ext_vector_type(4)));

// 'user' may be int64 (jax x64) or int32. Detect from data.
__device__ __forceinline__ bool user_is_i64(const void* uptr) {
    const int* u = (const int*)uptr;
    return (u[1] | u[3] | u[5] | u[7]) == 0;
}
__device__ __forceinline__ int load_user(const void* uptr, int b, bool is64) {
    return is64 ? (int)((const long long*)uptr)[b] : ((const int*)uptr)[b];
}
__device__ __forceinline__ int sample_node(const void* user, const int* pos,
                                           const int* neg, int which, int b,
                                           bool is64) {
    if (which == 0) return load_user(user, b, is64);
    return N_USERS + (which == 1 ? pos[b] : neg[b]);
}

// edge payload: (fp16bits(val) << 17) | col.  val in [0,1) => sign bit 0,
// 15 significant fp16 bits; col < 2^17.  word 0 => col 0, val +0.0.
__device__ __forceinline__ float unpack_val(unsigned w) {
    unsigned short us = (unsigned short)(w >> 17);
    _Float16 h = __builtin_bit_cast(_Float16, us);
    return (float)h;
}

// ---------------------------------------------------------------------------
// init (+ fused gather0): f16 <- fp16(emb); out[:, 0:64] <- emb rows (fp32 exact)
// ---------------------------------------------------------------------------
__global__ void init_kernel(const float* __restrict__ emb,
                            _Float16* __restrict__ f16,
                            const void* __restrict__ user,
                            const int* __restrict__ pos,
                            const int* __restrict__ neg,
                            float* __restrict__ out) {
    int i = blockIdx.x * 256 + threadIdx.x;
    if (i < N_NODES * EMB) {
        f16[i] = (_Float16)emb[i];
    } else {
        int j = i - N_NODES * EMB;
        if (j < 3 * BATCH * EMB) {
            bool is64 = user_is_i64(user);
            int which = j / (BATCH * EMB);
            int rem   = j % (BATCH * EMB);
            int b = rem >> 6, d = rem & 63;
            int node = sample_node(user, pos, neg, which, b, is64);
            out[(which * BATCH + b) * CONCAT + d] = emb[node * EMB + d];
        }
    }
}

// ---------------------------------------------------------------------------
// CSR build: histogram -> scan -> bin (row-sorted packed 4B payload)
// ---------------------------------------------------------------------------
__global__ void count_kernel(const int* __restrict__ row, int* __restrict__ cnt) {
    int e = blockIdx.x * 256 + threadIdx.x;
    if (e < NNZ) atomicAdd(&cnt[row[e]], 1);
}

__global__ __launch_bounds__(256) void scan_blocks_kernel(
    const int* __restrict__ cnt, int* __restrict__ off, int* __restrict__ bsum) {
    __shared__ int s[256];
    int t = threadIdx.x, b = blockIdx.x;
    int base = b * 1024 + t * 4;
    int v0 = (base + 0 < N_NODES) ? cnt[base + 0] : 0;
    int v1 = (base + 1 < N_NODES) ? cnt[base + 1] : 0;
    int v2 = (base + 2 < N_NODES) ? cnt[base + 2] : 0;
    int v3 = (base + 3 < N_NODES) ? cnt[base + 3] : 0;
    int tsum = v0 + v1 + v2 + v3;
    s[t] = tsum;
    __syncthreads();
    for (int d = 1; d < 256; d <<= 1) {
        int x = (t >= d) ? s[t - d] : 0;
        __syncthreads();
        s[t] += x;
        __syncthreads();
    }
    int excl = s[t] - tsum;
    if (base + 0 < N_NODES) off[base + 0] = excl;
    if (base + 1 < N_NODES) off[base + 1] = excl + v0;
    if (base + 2 < N_NODES) off[base + 2] = excl + v0 + v1;
    if (base + 3 < N_NODES) off[base + 3] = excl + v0 + v1 + v2;
    if (t == 255) bsum[b] = s[255];
}

// per-block redundant prefix of bsum (123 entries) + add
__global__ __launch_bounds__(256) void scan_add_kernel(
    int* __restrict__ off, const int* __restrict__ bsum, int* __restrict__ cursor) {
    __shared__ int sb[NBLK_SCAN];
    int t = threadIdx.x;
    if (t < NBLK_SCAN) sb[t] = bsum[t];
    __syncthreads();
    if (t == 0) {
        int run = 0;
        for (int b = 0; b < NBLK_SCAN; ++b) { int x = sb[b]; sb[b] = run; run += x; }
    }
    __syncthreads();
    int i = blockIdx.x * 256 + t;
    if (i < N_NODES) {
        int v = off[i] + sb[i >> 10];
        off[i] = v;
        cursor[i] = v;
    }
    if (i == 0) off[N_NODES] = NNZ;
}

__global__ void bin_kernel(const int* __restrict__ row, const int* __restrict__ col,
                           const float* __restrict__ vals,
                           int* __restrict__ cursor, unsigned* __restrict__ se) {
    int e = blockIdx.x * 256 + threadIdx.x;
    if (e >= NNZ) return;
    int r = row[e];
    _Float16 hv = (_Float16)vals[e];
    unsigned hb = (unsigned)__builtin_bit_cast(unsigned short, hv);
    unsigned w = (hb << 17) | (unsigned)col[e];
    int p = atomicAdd(&cursor[r], 1);
    se[p] = w;
}

// ---------------------------------------------------------------------------
// SpMM gather: one wave per node; packed 4B edge words; fp16 feat rows (128B).
//   agg16[n] = fp16( sum_e val_e * fin[col_e] )
// ---------------------------------------------------------------------------
__global__ __launch_bounds__(256) void spmm_kernel(
    const int* __restrict__ off, const unsigned* __restrict__ se,
    const _Float16* __restrict__ fin, _Float16* __restrict__ agg16) {
    int w = blockIdx.x * 4 + (threadIdx.x >> 6);
    int lane = threadIdx.x & 63;
    if (w >= N_NODES) return;
    int j = off[w], end = off[w + 1];
    float acc = 0.f;
    while (j < end) {
        int cnt = end - j;
        unsigned ev[8];
        #pragma unroll
        for (int t = 0; t < 8; ++t)
            ev[t] = (t < cnt) ? se[j + t] : 0u;   // 0 => col 0, val +0.0
        #pragma unroll
        for (int t = 0; t < 8; ++t) {
            int c = (int)(ev[t] & 0x1FFFFu);
            acc += unpack_val(ev[t]) * (float)fin[c * EMB + lane];
        }
        j += 8;
    }
    agg16[w * EMB + lane] = (_Float16)acc;
}

// ---------------------------------------------------------------------------
// dense via MFMA f16: one wave = 16 nodes x 64 dims (4 n-tiles of 16).
//   p1 = lrelu(agg @ W1^T + b1); p2 = lrelu((agg*fin) @ W2^T + b2)
//   fout16 <- fp16(p1+p2)
// Layouts (gfx950, verified): A[m=lane&15][k=quad*8+j]; B[k=quad*8+j][n=lane&15];
// D: col=lane&15, row=quad*4+reg. g-frag = a-frag * f-frag elementwise (same [m][k]).
// ---------------------------------------------------------------------------
__global__ __launch_bounds__(256) void dense_kernel(
    const _Float16* __restrict__ agg16, const _Float16* __restrict__ fin,
    _Float16* __restrict__ fout,
    const float* __restrict__ W1, const float* __restrict__ b1,
    const float* __restrict__ W2, const float* __restrict__ b2, int layer) {

    const int tid = threadIdx.x, wave = tid >> 6, lane = tid & 63;
    const int quad = lane >> 4, lm = lane & 15;

    // Preload B-fragments (fp16 in registers): bwX[t][kh], t = n-tile, kh = K half
    half8 bw1[4][2], bw2[4][2];
    float bias1[4], bias2[4];
    const float* W1l = W1 + layer * EMB * EMB;
    const float* W2l = W2 + layer * EMB * EMB;
    #pragma unroll
    for (int t = 0; t < 4; ++t) {
        int n = t * 16 + lm;
        bias1[t] = b1[layer * EMB + n];
        bias2[t] = b2[layer * EMB + n];
        #pragma unroll
        for (int kh = 0; kh < 2; ++kh) {
            const float* p1 = W1l + n * EMB + kh * 32 + quad * 8;
            const float* p2 = W2l + n * EMB + kh * 32 + quad * 8;
            floatx4 wa = *(const floatx4*)p1, wb = *(const floatx4*)(p1 + 4);
            floatx4 xa = *(const floatx4*)p2, xb = *(const floatx4*)(p2 + 4);
            half8 h1, h2;
            #pragma unroll
            for (int i = 0; i < 4; ++i) {
                h1[i] = (_Float16)wa[i]; h1[4 + i] = (_Float16)wb[i];
                h2[i] = (_Float16)xa[i]; h2[4 + i] = (_Float16)xb[i];
            }
            bw1[t][kh] = h1;
            bw2[t][kh] = h2;
        }
    }

    for (int tile = blockIdx.x * 4 + wave; tile < NTILES; tile += gridDim.x * 4) {
        int nb = tile * 16;
        const half8* ap = (const half8*)(agg16 + (size_t)(nb + lm) * EMB + quad * 8);
        const half8* fp = (const half8*)(fin   + (size_t)(nb + lm) * EMB + quad * 8);
        half8 a0 = ap[0], a1 = ap[4];   // k in [0,32) and [32,64)
        half8 f0 = fp[0], f1 = fp[4];
        half8 g0 = a0 * f0, g1 = a1 * f1;   // v_pk_mul_f16, frag-space elementwise

        #pragma unroll
        for (int t = 0; t < 4; ++t) {
            floatx4 d1 = {0.f, 0.f, 0.f, 0.f}, d2 = {0.f, 0.f, 0.f, 0.f};
            d1 = __builtin_amdgcn_mfma_f32_16x16x32_f16(a0, bw1[t][0], d1, 0, 0, 0);
            d1 = __builtin_amdgcn_mfma_f32_16x16x32_f16(a1, bw1[t][1], d1, 0, 0, 0);
            d2 = __builtin_amdgcn_mfma_f32_16x16x32_f16(g0, bw2[t][0], d2, 0, 0, 0);
            d2 = __builtin_amdgcn_mfma_f32_16x16x32_f16(g1, bw2[t][1], d2, 0, 0, 0);
            int dim = t * 16 + lm;
            #pragma unroll
            for (int r = 0; r < 4; ++r) {
                int node = nb + quad * 4 + r;
                float p1v = d1[r] + bias1[t];
                p1v = p1v > 0.f ? p1v : 0.2f * p1v;
                float p2v = d2[r] + bias2[t];
                p2v = p2v > 0.f ? p2v : 0.2f * p2v;
                float nf = p1v + p2v;
                if (node < N_NODES)
                    fout[(size_t)node * EMB + dim] = (_Float16)nf;
            }
        }
    }
}

// ---------------------------------------------------------------------------
// gatherL: out[:, (l+1)*64 ...] <- l2_normalize(fp16 feat)[sampled nodes]
// ---------------------------------------------------------------------------
__global__ __launch_bounds__(256) void gatherL_kernel(
    const void* __restrict__ user, const int* __restrict__ pos,
    const int* __restrict__ neg, const _Float16* __restrict__ feat,
    float* __restrict__ out, int layer) {

    int w = blockIdx.x * 4 + (threadIdx.x >> 6);
    int lane = threadIdx.x & 63;
    if (w >= 3 * BATCH) return;
    bool is64 = user_is_i64(user);
    int which = w / BATCH, b = w % BATCH;
    int node = sample_node(user, pos, neg, which, b, is64);

    float f = (float)feat[(size_t)node * EMB + lane];
    float sq = f * f;
    #pragma unroll
    for (int off = 32; off; off >>= 1) sq += __shfl_xor(sq, off, 64);
    float norm = fmaxf(sqrtf(sq), 1e-12f);

    out[w * CONCAT + (layer + 1) * EMB + lane] = f / norm;
}

extern "C" void kernel_launch(void* const* d_in, const int* in_sizes, int n_in,
                              void* d_out, int out_size, void* d_ws, size_t ws_size,
                              hipStream_t stream) {
    const void* user = d_in[0];
    const int* pos  = (const int*)d_in[1];
    const int* neg  = (const int*)d_in[2];
    const int* row  = (const int*)d_in[3];
    const int* col  = (const int*)d_in[4];
    const float* vals = (const float*)d_in[5];
    const float* emb  = (const float*)d_in[6];
    const float* W1   = (const float*)d_in[7];
    const float* b1   = (const float*)d_in[8];
    const float* W2   = (const float*)d_in[9];
    const float* b2   = (const float*)d_in[10];

    // ws: f16a 16MB | f16b 16MB | agg16 16MB | ints ~1.9MB | se 5MB
    _Float16* f16a   = (_Float16*)d_ws;
    _Float16* f16b   = f16a + (size_t)N_PAD * EMB;
    _Float16* agg16  = f16b + (size_t)N_PAD * EMB;
    int*      off    = (int*)(agg16 + (size_t)N_PAD * EMB);
    int*      cursor = off + (N_NODES + 8);
    int*      cnt    = cursor + N_NODES;
    int*      bsum   = cnt + N_NODES;        // 123, padded to 128
    unsigned* se     = (unsigned*)(bsum + 128);

    float* out = (float*)d_out;

    // --- CSR build ---
    hipMemsetAsync(cnt, 0, (size_t)N_NODES * sizeof(int), stream);
    count_kernel<<<(NNZ + 255) / 256, 256, 0, stream>>>(row, cnt);
    scan_blocks_kernel<<<NBLK_SCAN, 256, 0, stream>>>(cnt, off, bsum);
    scan_add_kernel<<<(N_NODES + 255) / 256, 256, 0, stream>>>(off, bsum, cursor);
    bin_kernel<<<(NNZ + 255) / 256, 256, 0, stream>>>(row, col, vals, cursor, se);

    // --- init + gather0 fused ---
    init_kernel<<<(N_NODES * EMB + 3 * BATCH * EMB + 255) / 256, 256, 0, stream>>>(
        emb, f16a, user, pos, neg, out);

    const _Float16* fin = f16a;
    _Float16* fout = f16b;
    for (int l = 0; l < N_LAYERS; ++l) {
        spmm_kernel<<<(N_NODES + 3) / 4, 256, 0, stream>>>(off, se, fin, agg16);
        dense_kernel<<<1024, 256, 0, stream>>>(agg16, fin, fout, W1, b1, W2, b2, l);
        gatherL_kernel<<<(3 * BATCH + 3) / 4, 256, 0, stream>>>(
            user, pos, neg, fout, out, l);
        const _Float16* tmp = fout; fout = (_Float16*)fin; fin = (const _Float16*)tmp;
    }
}

// Round 9
// 413.188 us; speedup vs baseline: 1.9453x; 1.0956x over previous
//
#include <hip/hip_runtime.h>
#include <hip/hip_fp16.h>

#define N_USERS 50000
#define N_ITEMS 75000
#define N_NODES 125000
#define N_PAD   125008               // padded to multiple of 16 for MFMA tiles
#define NNZ     1250000
#define EMB     64
#define N_LAYERS 3
#define BATCH   4096
#define CONCAT  256
#define NTILES  ((N_NODES + 15) / 16)         // 7813

#define BROWS   128                           // rows per bucket
#define NB      ((N_NODES + BROWS - 1) / BROWS)   // 977 buckets
#define CHUNK   8192                          // edges per partition block
#define NCHUNK  ((NNZ + CHUNK - 1) / CHUNK)   // 153
#define BCAP    2048                          // max edges per bucket (21 sigma)

typedef _Float16 half8  __attribute__((ext_vector_type(8)));
typedef float    floatx4 __attribute__((ext_vector_type(4)));

// 'user' may be int64 (jax x64) or int32. Detect from data.
__device__ __forceinline__ bool user_is_i64(const void* uptr) {
    const int* u = (const int*)uptr;
    return (u[1] | u[3] | u[5] | u[7]) == 0;
}
__device__ __forceinline__ int load_user(const void* uptr, int b, bool is64) {
    return is64 ? (int)((const long long*)uptr)[b] : ((const int*)uptr)[b];
}
__device__ __forceinline__ int sample_node(const void* user, const int* pos,
                                           const int* neg, int which, int b,
                                           bool is64) {
    if (which == 0) return load_user(user, b, is64);
    return N_USERS + (which == 1 ? pos[b] : neg[b]);
}

// edge payload: (fp16bits(val) << 17) | col.  val in [0,1) => sign bit 0,
// 15 significant fp16 bits; col < 2^17.  word 0 => col 0, val +0.0.
__device__ __forceinline__ float unpack_val(unsigned w) {
    unsigned short us = (unsigned short)(w >> 17);
    _Float16 h = __builtin_bit_cast(_Float16, us);
    return (float)h;
}

// ---------------------------------------------------------------------------
// init (+ fused gather0): f16 <- fp16(emb); out[:, 0:64] <- emb rows (fp32 exact)
// ---------------------------------------------------------------------------
__global__ void init_kernel(const float* __restrict__ emb,
                            _Float16* __restrict__ f16,
                            const void* __restrict__ user,
                            const int* __restrict__ pos,
                            const int* __restrict__ neg,
                            float* __restrict__ out) {
    int i = blockIdx.x * 256 + threadIdx.x;
    if (i < N_NODES * EMB) {
        f16[i] = (_Float16)emb[i];
    } else {
        int j = i - N_NODES * EMB;
        if (j < 3 * BATCH * EMB) {
            bool is64 = user_is_i64(user);
            int which = j / (BATCH * EMB);
            int rem   = j % (BATCH * EMB);
            int b = rem >> 6, d = rem & 63;
            int node = sample_node(user, pos, neg, which, b, is64);
            out[(which * BATCH + b) * CONCAT + d] = emb[node * EMB + d];
        }
    }
}

// ---------------------------------------------------------------------------
// P1: bucket histogram (LDS-staged; one global atomic per (block,bucket))
// ---------------------------------------------------------------------------
__global__ __launch_bounds__(256) void bucket_hist_kernel(
    const int* __restrict__ row, int* __restrict__ bcnt) {
    __shared__ int h[NB];
    int t = threadIdx.x;
    for (int i = t; i < NB; i += 256) h[i] = 0;
    __syncthreads();
    int e0 = blockIdx.x * CHUNK;
    int e1 = e0 + CHUNK; if (e1 > NNZ) e1 = NNZ;
    for (int e = e0 + t; e < e1; e += 256)
        atomicAdd(&h[row[e] >> 7], 1);
    __syncthreads();
    for (int i = t; i < NB; i += 256)
        if (h[i]) atomicAdd(&bcnt[i], h[i]);
}

// ---------------------------------------------------------------------------
// P2: scan bucket counts (single block, 1024 threads); also CSR sentinel.
// ---------------------------------------------------------------------------
__global__ __launch_bounds__(1024) void bucket_scan_kernel(
    const int* __restrict__ bcnt, int* __restrict__ boff,
    int* __restrict__ bcur, int* __restrict__ off) {
    __shared__ int s[1024];
    int t = threadIdx.x;
    int v = (t < NB) ? bcnt[t] : 0;
    s[t] = v;
    __syncthreads();
    for (int d = 1; d < 1024; d <<= 1) {
        int x = (t >= d) ? s[t - d] : 0;
        __syncthreads();
        s[t] += x;
        __syncthreads();
    }
    int excl = s[t] - v;
    if (t < NB) { boff[t] = excl; bcur[t] = excl; }
    if (t == 0) { boff[NB] = NNZ; off[N_NODES] = NNZ; }
}

// ---------------------------------------------------------------------------
// P3: partition edges into buckets. Two passes per 8192-edge chunk:
//   a) LDS histogram  b) one global cursor-add per (block,bucket) -> runs are
//   contiguous per block => stores merge into full lines (line traffic ~payload).
// ---------------------------------------------------------------------------
__global__ __launch_bounds__(256) void partition_kernel(
    const int* __restrict__ row, const int* __restrict__ col,
    const float* __restrict__ vals, int* __restrict__ bcur,
    unsigned* __restrict__ sw, unsigned char* __restrict__ sr) {
    __shared__ int h[NB];
    __shared__ int base[NB];
    int t = threadIdx.x;
    int e0 = blockIdx.x * CHUNK;
    int e1 = e0 + CHUNK; if (e1 > NNZ) e1 = NNZ;
    for (int i = t; i < NB; i += 256) h[i] = 0;
    __syncthreads();
    for (int e = e0 + t; e < e1; e += 256)
        atomicAdd(&h[row[e] >> 7], 1);
    __syncthreads();
    for (int i = t; i < NB; i += 256) {
        int c = h[i];
        if (c) base[i] = atomicAdd(&bcur[i], c);
        h[i] = 0;
    }
    __syncthreads();
    for (int e = e0 + t; e < e1; e += 256) {
        int r = row[e];
        int b = r >> 7;
        int p = base[b] + atomicAdd(&h[b], 1);
        _Float16 hv = (_Float16)vals[e];
        unsigned hb = (unsigned)__builtin_bit_cast(unsigned short, hv);
        sw[p] = (hb << 17) | (unsigned)col[e];
        sr[p] = (unsigned char)(r & 127);
    }
}

// ---------------------------------------------------------------------------
// P4: in-bucket counting sort (one block per bucket, all LDS) -> final CSR:
//   per-row off[] and row-sorted se[], both written fully coalesced.
// ---------------------------------------------------------------------------
__global__ __launch_bounds__(256) void bucket_sort_kernel(
    const int* __restrict__ boff, const unsigned* __restrict__ sw,
    const unsigned char* __restrict__ sr, unsigned* __restrict__ se,
    int* __restrict__ off) {
    __shared__ unsigned ew[BCAP];
    __shared__ unsigned eo[BCAP];
    __shared__ unsigned char er[BCAP];
    __shared__ int rh[BROWS], rb[BROWS], rc[BROWS];
    __shared__ int s[256];

    int b = blockIdx.x, t = threadIdx.x;
    int s0 = boff[b];
    int n = boff[b + 1] - s0;           // <= BCAP (P < 1e-9 otherwise)
    if (t < BROWS) rh[t] = 0;
    __syncthreads();
    for (int i = t; i < n; i += 256) {
        ew[i] = sw[s0 + i];
        unsigned char r = sr[s0 + i];
        er[i] = r;
        atomicAdd(&rh[r], 1);
    }
    __syncthreads();
    s[t] = (t < BROWS) ? rh[t] : 0;     // inclusive scan over 256 (upper half 0)
    __syncthreads();
    for (int d = 1; d < 256; d <<= 1) {
        int x = (t >= d) ? s[t - d] : 0;
        __syncthreads();
        s[t] += x;
        __syncthreads();
    }
    if (t < BROWS) {
        int excl = s[t] - rh[t];
        rb[t] = excl;
        rc[t] = 0;
        int r = b * BROWS + t;
        if (r < N_NODES) off[r] = s0 + excl;
    }
    __syncthreads();
    for (int i = t; i < n; i += 256) {
        unsigned char r = er[i];
        int p = rb[r] + atomicAdd(&rc[r], 1);
        eo[p] = ew[i];
    }
    __syncthreads();
    for (int i = t; i < n; i += 256)
        se[s0 + i] = eo[i];
}

// ---------------------------------------------------------------------------
// SpMM gather: one wave per node; packed 4B edge words; fp16 feat rows (128B).
//   agg16[n] = fp16( sum_e val_e * fin[col_e] )
// ---------------------------------------------------------------------------
__global__ __launch_bounds__(256) void spmm_kernel(
    const int* __restrict__ off, const unsigned* __restrict__ se,
    const _Float16* __restrict__ fin, _Float16* __restrict__ agg16) {
    int w = blockIdx.x * 4 + (threadIdx.x >> 6);
    int lane = threadIdx.x & 63;
    if (w >= N_NODES) return;
    int j = off[w], end = off[w + 1];
    float acc = 0.f;
    while (j < end) {
        int cnt = end - j;
        unsigned ev[8];
        #pragma unroll
        for (int t = 0; t < 8; ++t)
            ev[t] = (t < cnt) ? se[j + t] : 0u;   // 0 => col 0, val +0.0
        #pragma unroll
        for (int t = 0; t < 8; ++t) {
            int c = (int)(ev[t] & 0x1FFFFu);
            acc += unpack_val(ev[t]) * (float)fin[c * EMB + lane];
        }
        j += 8;
    }
    agg16[w * EMB + lane] = (_Float16)acc;
}

// ---------------------------------------------------------------------------
// dense via MFMA f16: one wave = 16 nodes x 64 dims (4 n-tiles of 16).
//   p1 = lrelu(agg @ W1^T + b1); p2 = lrelu((agg*fin) @ W2^T + b2)
//   fout16 <- fp16(p1+p2)
// ---------------------------------------------------------------------------
__global__ __launch_bounds__(256) void dense_kernel(
    const _Float16* __restrict__ agg16, const _Float16* __restrict__ fin,
    _Float16* __restrict__ fout,
    const float* __restrict__ W1, const float* __restrict__ b1,
    const float* __restrict__ W2, const float* __restrict__ b2, int layer) {

    const int tid = threadIdx.x, wave = tid >> 6, lane = tid & 63;
    const int quad = lane >> 4, lm = lane & 15;

    half8 bw1[4][2], bw2[4][2];
    float bias1[4], bias2[4];
    const float* W1l = W1 + layer * EMB * EMB;
    const float* W2l = W2 + layer * EMB * EMB;
    #pragma unroll
    for (int t = 0; t < 4; ++t) {
        int n = t * 16 + lm;
        bias1[t] = b1[layer * EMB + n];
        bias2[t] = b2[layer * EMB + n];
        #pragma unroll
        for (int kh = 0; kh < 2; ++kh) {
            const float* p1 = W1l + n * EMB + kh * 32 + quad * 8;
            const float* p2 = W2l + n * EMB + kh * 32 + quad * 8;
            floatx4 wa = *(const floatx4*)p1, wb = *(const floatx4*)(p1 + 4);
            floatx4 xa = *(const floatx4*)p2, xb = *(const floatx4*)(p2 + 4);
            half8 h1, h2;
            #pragma unroll
            for (int i = 0; i < 4; ++i) {
                h1[i] = (_Float16)wa[i]; h1[4 + i] = (_Float16)wb[i];
                h2[i] = (_Float16)xa[i]; h2[4 + i] = (_Float16)xb[i];
            }
            bw1[t][kh] = h1;
            bw2[t][kh] = h2;
        }
    }

    for (int tile = blockIdx.x * 4 + wave; tile < NTILES; tile += gridDim.x * 4) {
        int nb = tile * 16;
        const half8* ap = (const half8*)(agg16 + (size_t)(nb + lm) * EMB + quad * 8);
        const half8* fp = (const half8*)(fin   + (size_t)(nb + lm) * EMB + quad * 8);
        half8 a0 = ap[0], a1 = ap[4];   // k in [0,32) and [32,64)
        half8 f0 = fp[0], f1 = fp[4];
        half8 g0 = a0 * f0, g1 = a1 * f1;

        #pragma unroll
        for (int t = 0; t < 4; ++t) {
            floatx4 d1 = {0.f, 0.f, 0.f, 0.f}, d2 = {0.f, 0.f, 0.f, 0.f};
            d1 = __builtin_amdgcn_mfma_f32_16x16x32_f16(a0, bw1[t][0], d1, 0, 0, 0);
            d1 = __builtin_amdgcn_mfma_f32_16x16x32_f16(a1, bw1[t][1], d1, 0, 0, 0);
            d2 = __builtin_amdgcn_mfma_f32_16x16x32_f16(g0, bw2[t][0], d2, 0, 0, 0);
            d2 = __builtin_amdgcn_mfma_f32_16x16x32_f16(g1, bw2[t][1], d2, 0, 0, 0);
            int dim = t * 16 + lm;
            #pragma unroll
            for (int r = 0; r < 4; ++r) {
                int node = nb + quad * 4 + r;
                float p1v = d1[r] + bias1[t];
                p1v = p1v > 0.f ? p1v : 0.2f * p1v;
                float p2v = d2[r] + bias2[t];
                p2v = p2v > 0.f ? p2v : 0.2f * p2v;
                float nf = p1v + p2v;
                if (node < N_NODES)
                    fout[(size_t)node * EMB + dim] = (_Float16)nf;
            }
        }
    }
}

// ---------------------------------------------------------------------------
// gatherL: out[:, (l+1)*64 ...] <- l2_normalize(fp16 feat)[sampled nodes]
// ---------------------------------------------------------------------------
__global__ __launch_bounds__(256) void gatherL_kernel(
    const void* __restrict__ user, const int* __restrict__ pos,
    const int* __restrict__ neg, const _Float16* __restrict__ feat,
    float* __restrict__ out, int layer) {

    int w = blockIdx.x * 4 + (threadIdx.x >> 6);
    int lane = threadIdx.x & 63;
    if (w >= 3 * BATCH) return;
    bool is64 = user_is_i64(user);
    int which = w / BATCH, b = w % BATCH;
    int node = sample_node(user, pos, neg, which, b, is64);

    float f = (float)feat[(size_t)node * EMB + lane];
    float sq = f * f;
    #pragma unroll
    for (int off = 32; off; off >>= 1) sq += __shfl_xor(sq, off, 64);
    float norm = fmaxf(sqrtf(sq), 1e-12f);

    out[w * CONCAT + (layer + 1) * EMB + lane] = f / norm;
}

extern "C" void kernel_launch(void* const* d_in, const int* in_sizes, int n_in,
                              void* d_out, int out_size, void* d_ws, size_t ws_size,
                              hipStream_t stream) {
    const void* user = d_in[0];
    const int* pos  = (const int*)d_in[1];
    const int* neg  = (const int*)d_in[2];
    const int* row  = (const int*)d_in[3];
    const int* col  = (const int*)d_in[4];
    const float* vals = (const float*)d_in[5];
    const float* emb  = (const float*)d_in[6];
    const float* W1   = (const float*)d_in[7];
    const float* b1   = (const float*)d_in[8];
    const float* W2   = (const float*)d_in[9];
    const float* b2   = (const float*)d_in[10];

    // ws layout:
    _Float16* f16a   = (_Float16*)d_ws;                       // 16 MB
    _Float16* f16b   = f16a + (size_t)N_PAD * EMB;            // 16 MB
    _Float16* agg16  = f16b + (size_t)N_PAD * EMB;            // 16 MB
    int*      off    = (int*)(agg16 + (size_t)N_PAD * EMB);   // N_NODES+8
    int*      bcnt   = off + (N_NODES + 8);                   // NB+8
    int*      boff   = bcnt + (NB + 8);                       // NB+8
    int*      bcur   = boff + (NB + 8);                       // NB+8
    unsigned* sw     = (unsigned*)(bcur + (NB + 8));          // 5 MB staged words
    unsigned* se     = sw + NNZ;                              // 5 MB final CSR
    unsigned char* sr = (unsigned char*)(se + NNZ);           // 1.25 MB row-locals

    float* out = (float*)d_out;

    // --- CSR build: bucket counting sort ---
    hipMemsetAsync(bcnt, 0, (size_t)NB * sizeof(int), stream);
    bucket_hist_kernel<<<NCHUNK, 256, 0, stream>>>(row, bcnt);
    bucket_scan_kernel<<<1, 1024, 0, stream>>>(bcnt, boff, bcur, off);
    partition_kernel<<<NCHUNK, 256, 0, stream>>>(row, col, vals, bcur, sw, sr);
    bucket_sort_kernel<<<NB, 256, 0, stream>>>(boff, sw, sr, se, off);

    // --- init + gather0 fused ---
    init_kernel<<<(N_NODES * EMB + 3 * BATCH * EMB + 255) / 256, 256, 0, stream>>>(
        emb, f16a, user, pos, neg, out);

    const _Float16* fin = f16a;
    _Float16* fout = f16b;
    for (int l = 0; l < N_LAYERS; ++l) {
        spmm_kernel<<<(N_NODES + 3) / 4, 256, 0, stream>>>(off, se, fin, agg16);
        dense_kernel<<<1024, 256, 0, stream>>>(agg16, fin, fout, W1, b1, W2, b2, l);
        gatherL_kernel<<<(3 * BATCH + 3) / 4, 256, 0, stream>>>(
            user, pos, neg, fout, out, l);
        const _Float16* tmp = fout; fout = (_Float16*)fin; fin = (const _Float16*)tmp;
    }
}

// Round 10
// 364.322 us; speedup vs baseline: 2.2063x; 1.1341x over previous
//
#include <hip/hip_runtime.h>
#include <hip/hip_fp16.h>

#define N_USERS 50000
#define N_ITEMS 75000
#define N_NODES 125000
#define N_PAD   125008               // padded to multiple of 16 for MFMA tiles
#define NNZ     1250000
#define EMB     64
#define N_LAYERS 3
#define BATCH   4096
#define CONCAT  256
#define NTILES  ((N_NODES + 15) / 16)         // 7813

#define BROWS   128                           // rows per bucket
#define NB      ((N_NODES + BROWS - 1) / BROWS)   // 977 buckets
#define CHUNK   4096                          // edges per partition block
#define NCHUNK  ((NNZ + CHUNK - 1) / CHUNK)   // 306
#define BCAP    1600                          // bucket capacity (mean 1280, +9 sigma)

typedef _Float16 half8  __attribute__((ext_vector_type(8)));
typedef float    floatx4 __attribute__((ext_vector_type(4)));

// 'user' may be int64 (jax x64) or int32. Detect from data.
__device__ __forceinline__ bool user_is_i64(const void* uptr) {
    const int* u = (const int*)uptr;
    return (u[1] | u[3] | u[5] | u[7]) == 0;
}
__device__ __forceinline__ int load_user(const void* uptr, int b, bool is64) {
    return is64 ? (int)((const long long*)uptr)[b] : ((const int*)uptr)[b];
}
__device__ __forceinline__ int sample_node(const void* user, const int* pos,
                                           const int* neg, int which, int b,
                                           bool is64) {
    if (which == 0) return load_user(user, b, is64);
    return N_USERS + (which == 1 ? pos[b] : neg[b]);
}

// staged record (8B): [bits 24..37] fp16(val) (val<2 => 14 bits) | [17..23] row&127 | [0..16] col
// final se word (4B): (fp16bits << 17) | col ;  word 0 => col 0, val +0.0
__device__ __forceinline__ float unpack_val(unsigned w) {
    unsigned short us = (unsigned short)(w >> 17);
    _Float16 h = __builtin_bit_cast(_Float16, us);
    return (float)h;
}

// ---------------------------------------------------------------------------
// init (+ fused gather0): f16 <- fp16(emb); out[:, 0:64] <- emb rows (fp32 exact)
// ---------------------------------------------------------------------------
__global__ void init_kernel(const float* __restrict__ emb,
                            _Float16* __restrict__ f16,
                            const void* __restrict__ user,
                            const int* __restrict__ pos,
                            const int* __restrict__ neg,
                            float* __restrict__ out) {
    int i = blockIdx.x * 256 + threadIdx.x;
    if (i < N_NODES * EMB) {
        f16[i] = (_Float16)emb[i];
    } else {
        int j = i - N_NODES * EMB;
        if (j < 3 * BATCH * EMB) {
            bool is64 = user_is_i64(user);
            int which = j / (BATCH * EMB);
            int rem   = j % (BATCH * EMB);
            int b = rem >> 6, d = rem & 63;
            int node = sample_node(user, pos, neg, which, b, is64);
            out[(which * BATCH + b) * CONCAT + d] = emb[node * EMB + d];
        }
    }
}

// ---------------------------------------------------------------------------
// P1: partition edges into fixed-capacity buckets (fused histogram+alloc).
// Per 4096-edge chunk: LDS hist -> one global atomicAdd per (block,bucket)
// -> contiguous 8B-record runs (line-merged stores).
// ---------------------------------------------------------------------------
__global__ __launch_bounds__(256) void partition_kernel(
    const int* __restrict__ row, const int* __restrict__ col,
    const float* __restrict__ vals, int* __restrict__ bcnt,
    unsigned long long* __restrict__ sw8) {
    __shared__ int h[NB];
    __shared__ int base[NB];
    int t = threadIdx.x;
    int e0 = blockIdx.x * CHUNK;
    int e1 = e0 + CHUNK; if (e1 > NNZ) e1 = NNZ;
    for (int i = t; i < NB; i += 256) h[i] = 0;
    __syncthreads();
    for (int e = e0 + t; e < e1; e += 256)
        atomicAdd(&h[row[e] >> 7], 1);
    __syncthreads();
    for (int i = t; i < NB; i += 256) {
        int c = h[i];
        if (c) base[i] = atomicAdd(&bcnt[i], c);
        h[i] = 0;
    }
    __syncthreads();
    for (int e = e0 + t; e < e1; e += 256) {
        int r = row[e];
        int b = r >> 7;
        int p = base[b] + atomicAdd(&h[b], 1);
        _Float16 hv = (_Float16)vals[e];
        unsigned hb = (unsigned)__builtin_bit_cast(unsigned short, hv);
        unsigned long long rec = ((unsigned long long)hb << 24)
                               | ((unsigned)(r & 127) << 17)
                               | (unsigned)col[e];
        sw8[(size_t)b * BCAP + p] = rec;
    }
}

// ---------------------------------------------------------------------------
// P2: scan bucket counts -> boff (final se layout); CSR sentinel.
// ---------------------------------------------------------------------------
__global__ __launch_bounds__(1024) void bucket_scan_kernel(
    const int* __restrict__ bcnt, int* __restrict__ boff, int* __restrict__ off) {
    __shared__ int s[1024];
    int t = threadIdx.x;
    int v = (t < NB) ? bcnt[t] : 0;
    s[t] = v;
    __syncthreads();
    for (int d = 1; d < 1024; d <<= 1) {
        int x = (t >= d) ? s[t - d] : 0;
        __syncthreads();
        s[t] += x;
        __syncthreads();
    }
    if (t < NB) boff[t] = s[t] - v;
    if (t == 0) { boff[NB] = NNZ; off[N_NODES] = NNZ; }
}

// ---------------------------------------------------------------------------
// P3: in-bucket counting sort (one block per bucket, all LDS) -> final CSR:
//   per-row off[] and row-sorted 4B se[], both written fully coalesced.
// ---------------------------------------------------------------------------
__global__ __launch_bounds__(256) void bucket_sort_kernel(
    const int* __restrict__ bcnt, const int* __restrict__ boff,
    const unsigned long long* __restrict__ sw8,
    unsigned* __restrict__ se, int* __restrict__ off) {
    __shared__ unsigned long long ew[BCAP];
    __shared__ unsigned eo[BCAP];
    __shared__ int rh[BROWS], rb[BROWS], rc[BROWS];
    __shared__ int s[256];

    int b = blockIdx.x, t = threadIdx.x;
    int n = bcnt[b];
    int s0 = boff[b];
    if (t < BROWS) rh[t] = 0;
    __syncthreads();
    const unsigned long long* src = sw8 + (size_t)b * BCAP;
    for (int i = t; i < n; i += 256) {
        unsigned long long rec = src[i];
        ew[i] = rec;
        atomicAdd(&rh[(int)((rec >> 17) & 127)], 1);
    }
    __syncthreads();
    s[t] = (t < BROWS) ? rh[t] : 0;
    __syncthreads();
    for (int d = 1; d < 256; d <<= 1) {
        int x = (t >= d) ? s[t - d] : 0;
        __syncthreads();
        s[t] += x;
        __syncthreads();
    }
    if (t < BROWS) {
        int excl = s[t] - rh[t];
        rb[t] = excl;
        rc[t] = 0;
        int r = b * BROWS + t;
        if (r < N_NODES) off[r] = s0 + excl;
    }
    __syncthreads();
    for (int i = t; i < n; i += 256) {
        unsigned long long rec = ew[i];
        int r = (int)((rec >> 17) & 127);
        int p = rb[r] + atomicAdd(&rc[r], 1);
        eo[p] = (unsigned)(((rec >> 24) << 17) | (rec & 0x1FFFFULL));
    }
    __syncthreads();
    for (int i = t; i < n; i += 256)
        se[s0 + i] = eo[i];
}

// ---------------------------------------------------------------------------
// SpMM gather: one wave per node; packed 4B edge words; fp16 feat rows (128B).
// 16-deep edge batch: mean degree 10 => one batch, 16 loads in flight.
// ---------------------------------------------------------------------------
__global__ __launch_bounds__(256) void spmm_kernel(
    const int* __restrict__ off, const unsigned* __restrict__ se,
    const _Float16* __restrict__ fin, _Float16* __restrict__ agg16) {
    int w = blockIdx.x * 4 + (threadIdx.x >> 6);
    int lane = threadIdx.x & 63;
    if (w >= N_NODES) return;
    int j = off[w], end = off[w + 1];
    float acc = 0.f;
    while (j < end) {
        int cnt = end - j;
        unsigned ev[16];
        #pragma unroll
        for (int t = 0; t < 16; ++t)
            ev[t] = (t < cnt) ? se[j + t] : 0u;   // 0 => col 0, val +0.0
        #pragma unroll
        for (int t = 0; t < 16; ++t) {
            int c = (int)(ev[t] & 0x1FFFFu);
            acc += unpack_val(ev[t]) * (float)fin[c * EMB + lane];
        }
        j += 16;
    }
    agg16[w * EMB + lane] = (_Float16)acc;
}

// ---------------------------------------------------------------------------
// dense via MFMA f16: one wave = 16 nodes x 64 dims (4 n-tiles of 16).
//   p1 = lrelu(agg @ W1^T + b1); p2 = lrelu((agg*fin) @ W2^T + b2)
//   fout16 <- fp16(p1+p2)
// ---------------------------------------------------------------------------
__global__ __launch_bounds__(256) void dense_kernel(
    const _Float16* __restrict__ agg16, const _Float16* __restrict__ fin,
    _Float16* __restrict__ fout,
    const float* __restrict__ W1, const float* __restrict__ b1,
    const float* __restrict__ W2, const float* __restrict__ b2, int layer) {

    const int tid = threadIdx.x, wave = tid >> 6, lane = tid & 63;
    const int quad = lane >> 4, lm = lane & 15;

    half8 bw1[4][2], bw2[4][2];
    float bias1[4], bias2[4];
    const float* W1l = W1 + layer * EMB * EMB;
    const float* W2l = W2 + layer * EMB * EMB;
    #pragma unroll
    for (int t = 0; t < 4; ++t) {
        int n = t * 16 + lm;
        bias1[t] = b1[layer * EMB + n];
        bias2[t] = b2[layer * EMB + n];
        #pragma unroll
        for (int kh = 0; kh < 2; ++kh) {
            const float* p1 = W1l + n * EMB + kh * 32 + quad * 8;
            const float* p2 = W2l + n * EMB + kh * 32 + quad * 8;
            floatx4 wa = *(const floatx4*)p1, wb = *(const floatx4*)(p1 + 4);
            floatx4 xa = *(const floatx4*)p2, xb = *(const floatx4*)(p2 + 4);
            half8 h1, h2;
            #pragma unroll
            for (int i = 0; i < 4; ++i) {
                h1[i] = (_Float16)wa[i]; h1[4 + i] = (_Float16)wb[i];
                h2[i] = (_Float16)xa[i]; h2[4 + i] = (_Float16)xb[i];
            }
            bw1[t][kh] = h1;
            bw2[t][kh] = h2;
        }
    }

    for (int tile = blockIdx.x * 4 + wave; tile < NTILES; tile += gridDim.x * 4) {
        int nb = tile * 16;
        const half8* ap = (const half8*)(agg16 + (size_t)(nb + lm) * EMB + quad * 8);
        const half8* fp = (const half8*)(fin   + (size_t)(nb + lm) * EMB + quad * 8);
        half8 a0 = ap[0], a1 = ap[4];   // k in [0,32) and [32,64)
        half8 f0 = fp[0], f1 = fp[4];
        half8 g0 = a0 * f0, g1 = a1 * f1;

        #pragma unroll
        for (int t = 0; t < 4; ++t) {
            floatx4 d1 = {0.f, 0.f, 0.f, 0.f}, d2 = {0.f, 0.f, 0.f, 0.f};
            d1 = __builtin_amdgcn_mfma_f32_16x16x32_f16(a0, bw1[t][0], d1, 0, 0, 0);
            d1 = __builtin_amdgcn_mfma_f32_16x16x32_f16(a1, bw1[t][1], d1, 0, 0, 0);
            d2 = __builtin_amdgcn_mfma_f32_16x16x32_f16(g0, bw2[t][0], d2, 0, 0, 0);
            d2 = __builtin_amdgcn_mfma_f32_16x16x32_f16(g1, bw2[t][1], d2, 0, 0, 0);
            int dim = t * 16 + lm;
            #pragma unroll
            for (int r = 0; r < 4; ++r) {
                int node = nb + quad * 4 + r;
                float p1v = d1[r] + bias1[t];
                p1v = p1v > 0.f ? p1v : 0.2f * p1v;
                float p2v = d2[r] + bias2[t];
                p2v = p2v > 0.f ? p2v : 0.2f * p2v;
                float nf = p1v + p2v;
                if (node < N_NODES)
                    fout[(size_t)node * EMB + dim] = (_Float16)nf;
            }
        }
    }
}

// ---------------------------------------------------------------------------
// gatherL: out[:, (l+1)*64 ...] <- l2_normalize(fp16 feat)[sampled nodes]
// ---------------------------------------------------------------------------
__global__ __launch_bounds__(256) void gatherL_kernel(
    const void* __restrict__ user, const int* __restrict__ pos,
    const int* __restrict__ neg, const _Float16* __restrict__ feat,
    float* __restrict__ out, int layer) {

    int w = blockIdx.x * 4 + (threadIdx.x >> 6);
    int lane = threadIdx.x & 63;
    if (w >= 3 * BATCH) return;
    bool is64 = user_is_i64(user);
    int which = w / BATCH, b = w % BATCH;
    int node = sample_node(user, pos, neg, which, b, is64);

    float f = (float)feat[(size_t)node * EMB + lane];
    float sq = f * f;
    #pragma unroll
    for (int off = 32; off; off >>= 1) sq += __shfl_xor(sq, off, 64);
    float norm = fmaxf(sqrtf(sq), 1e-12f);

    out[w * CONCAT + (layer + 1) * EMB + lane] = f / norm;
}

extern "C" void kernel_launch(void* const* d_in, const int* in_sizes, int n_in,
                              void* d_out, int out_size, void* d_ws, size_t ws_size,
                              hipStream_t stream) {
    const void* user = d_in[0];
    const int* pos  = (const int*)d_in[1];
    const int* neg  = (const int*)d_in[2];
    const int* row  = (const int*)d_in[3];
    const int* col  = (const int*)d_in[4];
    const float* vals = (const float*)d_in[5];
    const float* emb  = (const float*)d_in[6];
    const float* W1   = (const float*)d_in[7];
    const float* b1   = (const float*)d_in[8];
    const float* W2   = (const float*)d_in[9];
    const float* b2   = (const float*)d_in[10];

    // ws layout (all offsets 8B-aligned):
    _Float16* f16a   = (_Float16*)d_ws;                       // 16 MB
    _Float16* f16b   = f16a + (size_t)N_PAD * EMB;            // 16 MB
    _Float16* agg16  = f16b + (size_t)N_PAD * EMB;            // 16 MB
    int*      off    = (int*)(agg16 + (size_t)N_PAD * EMB);   // 125008 ints
    int*      bcnt   = off + (N_NODES + 8);                   // 984 ints
    int*      boff   = bcnt + 984;                            // 984 ints
    unsigned long long* sw8 = (unsigned long long*)(boff + 984); // 977*1600*8 = 12.5 MB
    unsigned* se     = (unsigned*)(sw8 + (size_t)NB * BCAP);  // 5 MB final CSR

    float* out = (float*)d_out;

    // --- CSR build: fixed-cap bucket partition -> scan -> in-bucket sort ---
    hipMemsetAsync(bcnt, 0, (size_t)NB * sizeof(int), stream);
    partition_kernel<<<NCHUNK, 256, 0, stream>>>(row, col, vals, bcnt, sw8);
    bucket_scan_kernel<<<1, 1024, 0, stream>>>(bcnt, boff, off);
    bucket_sort_kernel<<<NB, 256, 0, stream>>>(bcnt, boff, sw8, se, off);

    // --- init + gather0 fused ---
    init_kernel<<<(N_NODES * EMB + 3 * BATCH * EMB + 255) / 256, 256, 0, stream>>>(
        emb, f16a, user, pos, neg, out);

    const _Float16* fin = f16a;
    _Float16* fout = f16b;
    for (int l = 0; l < N_LAYERS; ++l) {
        spmm_kernel<<<(N_NODES + 3) / 4, 256, 0, stream>>>(off, se, fin, agg16);
        dense_kernel<<<1024, 256, 0, stream>>>(agg16, fin, fout, W1, b1, W2, b2, l);
        gatherL_kernel<<<(3 * BATCH + 3) / 4, 256, 0, stream>>>(
            user, pos, neg, fout, out, l);
        const _Float16* tmp = fout; fout = (_Float16*)fin; fin = (const _Float16*)tmp;
    }
}